// Round 7
// baseline (306.215 us; speedup 1.0000x reference)
//
#include <hip/hip_runtime.h>

typedef unsigned short ushort_t;
typedef __attribute__((ext_vector_type(8))) short short8;
typedef __attribute__((ext_vector_type(4))) float floatx4;

#define DD 256
#define LL 3
#define GG 4
#define KK 128
#define UU 64
#define OUTN 10
#define HSTRIDE 264   // 256 + 8 bf16 pad; 528B row stride
#define MROWS 64      // rows per block; 4-wave blocks, 33.8 KB LDS -> 2 blocks/CU

__device__ __forceinline__ ushort_t f2bf(float f) {
  unsigned u = __builtin_bit_cast(unsigned, f);
  u = (u + 0x7FFFu + ((u >> 16) & 1u)) >> 16;
  return (ushort_t)u;
}

// pack two f32 -> two bf16: 2 adds + 1 v_perm_b32
__device__ __forceinline__ unsigned pack_bf2(float lo, float hi) {
  unsigned a = __builtin_bit_cast(unsigned, hi) + 0x8000u;
  unsigned b = __builtin_bit_cast(unsigned, lo) + 0x8000u;
  return __builtin_amdgcn_perm(a, b, 0x07060302u);
}

// tanh(x) = 1 - 2/(e^{2x}+1); branch-free, exact at overflow
__device__ __forceinline__ float fast_tanh(float x) {
  float e = __builtin_amdgcn_exp2f(x * 2.885390081777927f);
  return __builtin_fmaf(-2.0f, __builtin_amdgcn_rcpf(e + 1.0f), 1.0f);
}

// AT[l][n][k] = sum_{j: idx[l,g,j]==k} W[l,g,j,u]  (n = g*64+u), bf16.
// WoT[n][k] = W_out[k][n] (n<10 else 0), 16x256 bf16.
__global__ __launch_bounds__(256) void prep_kernel(
    const int* __restrict__ idx, const float* __restrict__ W,
    const float* __restrict__ Wout, ushort_t* __restrict__ AT,
    ushort_t* __restrict__ WoT) {
  int b = blockIdx.x;
  int t = threadIdx.x;
  if (b < LL * DD) {
    int l = b >> 8, n = b & 255, g = n >> 6, u = n & 63;
    __shared__ int sidx[KK];
    __shared__ float sw[KK];
    if (t < KK) {
      sidx[t] = idx[(l * GG + g) * KK + t];
      sw[t]   = W[((size_t)((l * GG + g) * KK + t)) * UU + u];
    }
    __syncthreads();
    float s = 0.f;
#pragma unroll 8
    for (int j = 0; j < KK; j++) s += (sidx[j] == t) ? sw[j] : 0.f;
    AT[(b << 8) | t] = f2bf(s);
  } else {
    int e2 = (b - LL * DD) * 256 + t;
    int n = e2 >> 8, k = e2 & 255;
    WoT[e2] = (n < OUTN) ? f2bf(Wout[k * OUTN + n]) : (ushort_t)0;
  }
}

// 16x16x32 MFMA, operand-swap: Aop = AT rows (u-dim), Bop = h rows (m-dim).
// Frag: index = lane&15, k = (lane>>4)*8 + j within a 32-k chunk.
// D: col = lane&15 -> m_local, row = (lane>>4)*4 + reg -> u_local.
// Block = 4 waves, 64 rows. Wave covers all 64 rows x 32 cols, in 2 column
// passes (p=0: cols [wave*32,+32), p=1: cols [128+wave*32,+32)).
// Per pass: A-slice register-resident (a0/a1[8] = 64 VGPR, loaded ONCE from
// L2, reused 8x), b read in batches of 8 independent ds_read_b128 (ping-pong
// across mt) -> ds_read latency amortized 8x and covered by 16 MFMAs/batch.
// acc[2][4][2] = 64 AGPR; ~212 unified regs -> 2 waves/SIMD, 2 blocks/CU.
__global__ __launch_bounds__(256, 2) void fused_kernel(
    const float* __restrict__ x, const float* __restrict__ bias,
    const float* __restrict__ bout, const ushort_t* __restrict__ AT,
    const ushort_t* __restrict__ WoT, float* __restrict__ out) {
  __shared__ ushort_t hbuf[MROWS * HSTRIDE];  // 33792 B -> 2 blocks/CU

  const int tid  = threadIdx.x;
  const int wave = tid >> 6;     // 0..3
  const int lane = tid & 63;
  const int quad = lane >> 4;
  const int l16  = lane & 15;
  const long row0 = (long)blockIdx.x * MROWS;

  // ---- stage x tile (64 x 256 fp32) -> bf16 LDS ----
  const float4* xv = (const float4*)(x + row0 * DD);
#pragma unroll
  for (int i = 0; i < 16; i++) {
    int f  = tid + i * 256;      // 0..4095 float4s, 64 per row
    int r  = f >> 6;
    int c4 = f & 63;
    float4 v = xv[r * 64 + c4];
    uint2 w;
    w.x = pack_bf2(v.x, v.y);
    w.y = pack_bf2(v.z, v.w);
    *(uint2*)&hbuf[r * HSTRIDE + c4 * 4] = w;
  }
  __syncthreads();

  const ushort_t* hsrc = hbuf + l16 * HSTRIDE + quad * 8;

  // ---- 3 levels ----
#pragma unroll 1
  for (int l = 0; l < 3; l++) {
    floatx4 acc[2][4][2];  // [pass][mt][nt]; bias folded into init
#pragma unroll
    for (int p = 0; p < 2; p++) {
#pragma unroll
      for (int nt = 0; nt < 2; nt++) {
        float4 bv = *(const float4*)&bias[l * DD + p * 128 + wave * 32 + nt * 16 + quad * 4];
        floatx4 ini = {bv.x, bv.y, bv.z, bv.w};
#pragma unroll
        for (int mt = 0; mt < 4; mt++) acc[p][mt][nt] = ini;
      }
    }

#pragma unroll
    for (int p = 0; p < 2; p++) {
      const ushort_t* Ab = AT + l * (DD * DD) + (p * 128 + wave * 32 + l16) * DD + quad * 8;
      // A-slice register-resident: 16 pipelined L2 loads, reused 8x each
      short8 a0[8], a1[8];
#pragma unroll
      for (int ks = 0; ks < 8; ks++) {
        a0[ks] = *(const short8*)&Ab[ks * 32];
        a1[ks] = *(const short8*)&Ab[16 * DD + ks * 32];
      }
      // b ping-pong: batch of 8 independent ds_read_b128 per row-group
      short8 b[2][8];
#pragma unroll
      for (int ks = 0; ks < 8; ks++) b[0][ks] = *(const short8*)&hsrc[ks * 32];
#pragma unroll
      for (int mt = 0; mt < 4; mt++) {
        const int cb = mt & 1, nb = cb ^ 1;
        if (mt < 3) {
#pragma unroll
          for (int ks = 0; ks < 8; ks++)
            b[nb][ks] = *(const short8*)&hsrc[(mt + 1) * 16 * HSTRIDE + ks * 32];
        }
#pragma unroll
        for (int ks = 0; ks < 8; ks++) {
          acc[p][mt][0] = __builtin_amdgcn_mfma_f32_16x16x32_bf16(a0[ks], b[cb][ks], acc[p][mt][0], 0, 0, 0);
          acc[p][mt][1] = __builtin_amdgcn_mfma_f32_16x16x32_bf16(a1[ks], b[cb][ks], acc[p][mt][1], 0, 0, 0);
        }
      }
    }
    __syncthreads();  // all hbuf reads done before overwrite

    // epilogue: lane owns row m = mt*16+l16; cols p*128 + wave*32 + nt*16 + quad*4
#pragma unroll
    for (int p = 0; p < 2; p++) {
#pragma unroll
      for (int mt = 0; mt < 4; mt++) {
#pragma unroll
        for (int nt = 0; nt < 2; nt++) {
          uint2 w;
          w.x = pack_bf2(fast_tanh(acc[p][mt][nt][0]), fast_tanh(acc[p][mt][nt][1]));
          w.y = pack_bf2(fast_tanh(acc[p][mt][nt][2]), fast_tanh(acc[p][mt][nt][3]));
          *(uint2*)&hbuf[(mt * 16 + l16) * HSTRIDE + p * 128 + wave * 32 + nt * 16 + quad * 4] = w;
        }
      }
    }
    __syncthreads();
  }

  // ---- final: Aop = WoT rows (o); wave handles rows [wave*16, +16) ----
  short8 wof[8];
#pragma unroll
  for (int ks = 0; ks < 8; ks++)
    wof[ks] = *(const short8*)&WoT[l16 * DD + ks * 32 + quad * 8];

  floatx4 accf = {0.f, 0.f, 0.f, 0.f};
#pragma unroll
  for (int ks = 0; ks < 8; ks++) {
    short8 bfr = *(const short8*)&hbuf[(wave * 16 + l16) * HSTRIDE + ks * 32 + quad * 8];
    accf = __builtin_amdgcn_mfma_f32_16x16x32_bf16(wof[ks], bfr, accf, 0, 0, 0);
  }
  const long obase = (row0 + wave * 16 + l16) * OUTN;
  if (quad < 2) {
    float4 p = {accf[0] + bout[quad * 4 + 0], accf[1] + bout[quad * 4 + 1],
                accf[2] + bout[quad * 4 + 2], accf[3] + bout[quad * 4 + 3]};
    *(float4*)&out[obase + quad * 4] = p;
  } else if (quad == 2) {
    float2 p = {accf[0] + bout[8], accf[1] + bout[9]};
    *(float2*)&out[obase + 8] = p;
  }
}

extern "C" void kernel_launch(void* const* d_in, const int* in_sizes, int n_in,
                              void* d_out, int out_size, void* d_ws, size_t ws_size,
                              hipStream_t stream) {
  const float* x    = (const float*)d_in[0];   // (131072, 256) fp32
  const int*   idx  = (const int*)d_in[1];     // (3, 4, 128) int32
  const float* W    = (const float*)d_in[2];   // (3, 4, 128, 64) fp32
  const float* b    = (const float*)d_in[3];   // (3, 4, 64) fp32
  const float* Wout = (const float*)d_in[4];   // (256, 10) fp32
  const float* bout = (const float*)d_in[5];   // (10,) fp32
  float* out = (float*)d_out;                  // (131072, 10) fp32

  ushort_t* AT  = (ushort_t*)d_ws;             // 3*256*256 bf16
  ushort_t* WoT = AT + LL * DD * DD;           // 16*256 bf16

  prep_kernel<<<LL * DD + 16, 256, 0, stream>>>(idx, W, Wout, AT, WoT);
  fused_kernel<<<131072 / MROWS, 256, 0, stream>>>(x, b, bout, AT, WoT, out);
}

// Round 8
// 304.074 us; speedup vs baseline: 1.0070x; 1.0070x over previous
//
#include <hip/hip_runtime.h>

typedef unsigned short ushort_t;
typedef __attribute__((ext_vector_type(8))) short short8;
typedef __attribute__((ext_vector_type(4))) float floatx4;

#define DD 256
#define LL 3
#define GG 4
#define KK 128
#define UU 64
#define OUTN 10
#define HSTRIDE 264   // 256 + 8 bf16 pad; 528B row stride
#define MROWS 64      // rows per block; 4-wave blocks, 33.8 KB LDS -> 3 blocks/CU

__device__ __forceinline__ ushort_t f2bf(float f) {
  unsigned u = __builtin_bit_cast(unsigned, f);
  u = (u + 0x7FFFu + ((u >> 16) & 1u)) >> 16;
  return (ushort_t)u;
}

// pack two f32 -> two bf16: 2 adds + 1 v_perm_b32
__device__ __forceinline__ unsigned pack_bf2(float lo, float hi) {
  unsigned a = __builtin_bit_cast(unsigned, hi) + 0x8000u;
  unsigned b = __builtin_bit_cast(unsigned, lo) + 0x8000u;
  return __builtin_amdgcn_perm(a, b, 0x07060302u);
}

// tanh(x) = 1 - 2/(e^{2x}+1); branch-free, exact at overflow
__device__ __forceinline__ float fast_tanh(float x) {
  float e = __builtin_amdgcn_exp2f(x * 2.885390081777927f);
  return __builtin_fmaf(-2.0f, __builtin_amdgcn_rcpf(e + 1.0f), 1.0f);
}

// AT[l][n][k] = sum_{j: idx[l,g,j]==k} W[l,g,j,u]  (n = g*64+u), bf16.
// WoT[n][k] = W_out[k][n] (n<10 else 0), 16x256 bf16.
__global__ __launch_bounds__(256) void prep_kernel(
    const int* __restrict__ idx, const float* __restrict__ W,
    const float* __restrict__ Wout, ushort_t* __restrict__ AT,
    ushort_t* __restrict__ WoT) {
  int b = blockIdx.x;
  int t = threadIdx.x;
  if (b < LL * DD) {
    int l = b >> 8, n = b & 255, g = n >> 6, u = n & 63;
    __shared__ int sidx[KK];
    __shared__ float sw[KK];
    if (t < KK) {
      sidx[t] = idx[(l * GG + g) * KK + t];
      sw[t]   = W[((size_t)((l * GG + g) * KK + t)) * UU + u];
    }
    __syncthreads();
    float s = 0.f;
#pragma unroll 8
    for (int j = 0; j < KK; j++) s += (sidx[j] == t) ? sw[j] : 0.f;
    AT[(b << 8) | t] = f2bf(s);
  } else {
    int e2 = (b - LL * DD) * 256 + t;
    int n = e2 >> 8, k = e2 & 255;
    WoT[e2] = (n < OUTN) ? f2bf(Wout[k * OUTN + n]) : (ushort_t)0;
  }
}

// 16x16x32 MFMA, operand-swap: Aop = AT rows (u-dim), Bop = h rows (m-dim).
// Frag: index = lane&15, k = (lane>>4)*8 + j within a 32-k chunk.
// D: col = lane&15 -> m_local, row = (lane>>4)*4 + reg -> u_local.
// Block = 4 waves, 64 rows. Wave w owns ALL 64 rows x cols [w*64,+64):
// MT=4, NT=4 -> per ks: 4 b ds_read_b128 (each feeds 4 MFMAs) + 4 a global
// (L2) + 16 MFMAs; a/b double-buffered across ks (static cur/nxt index).
// Emission order PINNED per unrolled iteration via sched_group_barrier:
// 4x DS_READ, 4x VMEM_READ, 16x MFMA -> loads issue one full iteration
// (~78+ cy of MFMA) ahead of their consumers; no compiler load-sinking.
__global__ __launch_bounds__(256, 3) void fused_kernel(
    const float* __restrict__ x, const float* __restrict__ bias,
    const float* __restrict__ bout, const ushort_t* __restrict__ AT,
    const ushort_t* __restrict__ WoT, float* __restrict__ out) {
  __shared__ ushort_t hbuf[MROWS * HSTRIDE];  // 33792 B -> 3 blocks/CU

  const int tid  = threadIdx.x;
  const int wave = tid >> 6;     // 0..3 : cols [wave*64, +64)
  const int lane = tid & 63;
  const int quad = lane >> 4;
  const int l16  = lane & 15;
  const long row0 = (long)blockIdx.x * MROWS;

  // ---- stage x tile (64 x 256 fp32) -> bf16 LDS ----
  const float4* xv = (const float4*)(x + row0 * DD);
#pragma unroll
  for (int i = 0; i < 16; i++) {
    int f  = tid + i * 256;      // 0..4095 float4s, 64 per row
    int r  = f >> 6;
    int c4 = f & 63;
    float4 v = xv[r * 64 + c4];
    uint2 w;
    w.x = pack_bf2(v.x, v.y);
    w.y = pack_bf2(v.z, v.w);
    *(uint2*)&hbuf[r * HSTRIDE + c4 * 4] = w;
  }
  __syncthreads();

  const ushort_t* hsrc = hbuf + l16 * HSTRIDE + quad * 8;

  // ---- 3 levels ----
#pragma unroll 1
  for (int l = 0; l < 3; l++) {
    const ushort_t* Ab = AT + l * (DD * DD) + (wave * 64 + l16) * DD + quad * 8;

    floatx4 acc[4][4];  // [mt][nt]; bias folded into init
#pragma unroll
    for (int nt = 0; nt < 4; nt++) {
      float4 bv = *(const float4*)&bias[l * DD + wave * 64 + nt * 16 + quad * 4];
      floatx4 ini = {bv.x, bv.y, bv.z, bv.w};
#pragma unroll
      for (int mt = 0; mt < 4; mt++) acc[mt][nt] = ini;
    }

    short8 a[2][4], b[2][4];
#pragma unroll
    for (int nt = 0; nt < 4; nt++) a[0][nt] = *(const short8*)&Ab[nt * 16 * DD];
#pragma unroll
    for (int mt = 0; mt < 4; mt++) b[0][mt] = *(const short8*)&hsrc[mt * 16 * HSTRIDE];

#pragma unroll
    for (int ks = 0; ks < 8; ks++) {
      const int cur = ks & 1, nxt = cur ^ 1;
      const int kn = ((ks + 1) & 7) * 32;  // wrap keeps SGB counts uniform
#pragma unroll
      for (int mt = 0; mt < 4; mt++)
        b[nxt][mt] = *(const short8*)&hsrc[mt * 16 * HSTRIDE + kn];
#pragma unroll
      for (int nt = 0; nt < 4; nt++)
        a[nxt][nt] = *(const short8*)&Ab[nt * 16 * DD + kn];
#pragma unroll
      for (int mt = 0; mt < 4; mt++) {
#pragma unroll
        for (int nt = 0; nt < 4; nt++)
          acc[mt][nt] = __builtin_amdgcn_mfma_f32_16x16x32_bf16(
              a[cur][nt], b[cur][mt], acc[mt][nt], 0, 0, 0);
      }
      // pin emitted order: loads for ks+1 BEFORE this ks's MFMAs get scheduled late
      __builtin_amdgcn_sched_group_barrier(0x100, 4, 0);  // 4x DS_READ
      __builtin_amdgcn_sched_group_barrier(0x020, 4, 0);  // 4x VMEM_READ
      __builtin_amdgcn_sched_group_barrier(0x008, 16, 0); // 16x MFMA
    }
    __syncthreads();  // all hbuf reads done before overwrite

    // epilogue: lane owns row m = mt*16+l16, cols wave*64+nt*16+quad*4..+3
#pragma unroll
    for (int mt = 0; mt < 4; mt++) {
#pragma unroll
      for (int nt = 0; nt < 4; nt++) {
        uint2 w;
        w.x = pack_bf2(fast_tanh(acc[mt][nt][0]), fast_tanh(acc[mt][nt][1]));
        w.y = pack_bf2(fast_tanh(acc[mt][nt][2]), fast_tanh(acc[mt][nt][3]));
        *(uint2*)&hbuf[(mt * 16 + l16) * HSTRIDE + wave * 64 + nt * 16 + quad * 4] = w;
      }
    }
    __syncthreads();
  }

  // ---- final: Aop = WoT rows (o); wave handles rows [wave*16, +16) ----
  short8 wof[8];
#pragma unroll
  for (int ks = 0; ks < 8; ks++)
    wof[ks] = *(const short8*)&WoT[l16 * DD + ks * 32 + quad * 8];

  floatx4 accf = {0.f, 0.f, 0.f, 0.f};
#pragma unroll
  for (int ks = 0; ks < 8; ks++) {
    short8 bfr = *(const short8*)&hbuf[(wave * 16 + l16) * HSTRIDE + ks * 32 + quad * 8];
    accf = __builtin_amdgcn_mfma_f32_16x16x32_bf16(wof[ks], bfr, accf, 0, 0, 0);
  }
  const long obase = (row0 + wave * 16 + l16) * OUTN;
  if (quad < 2) {
    float4 p = {accf[0] + bout[quad * 4 + 0], accf[1] + bout[quad * 4 + 1],
                accf[2] + bout[quad * 4 + 2], accf[3] + bout[quad * 4 + 3]};
    *(float4*)&out[obase + quad * 4] = p;
  } else if (quad == 2) {
    float2 p = {accf[0] + bout[8], accf[1] + bout[9]};
    *(float2*)&out[obase + 8] = p;
  }
}

extern "C" void kernel_launch(void* const* d_in, const int* in_sizes, int n_in,
                              void* d_out, int out_size, void* d_ws, size_t ws_size,
                              hipStream_t stream) {
  const float* x    = (const float*)d_in[0];   // (131072, 256) fp32
  const int*   idx  = (const int*)d_in[1];     // (3, 4, 128) int32
  const float* W    = (const float*)d_in[2];   // (3, 4, 128, 64) fp32
  const float* b    = (const float*)d_in[3];   // (3, 4, 64) fp32
  const float* Wout = (const float*)d_in[4];   // (256, 10) fp32
  const float* bout = (const float*)d_in[5];   // (10,) fp32
  float* out = (float*)d_out;                  // (131072, 10) fp32

  ushort_t* AT  = (ushort_t*)d_ws;             // 3*256*256 bf16
  ushort_t* WoT = AT + LL * DD * DD;           // 16*256 bf16

  prep_kernel<<<LL * DD + 16, 256, 0, stream>>>(idx, W, Wout, AT, WoT);
  fused_kernel<<<131072 / MROWS, 256, 0, stream>>>(x, b, bout, AT, WoT, out);
}

// Round 9
// 245.455 us; speedup vs baseline: 1.2475x; 1.2388x over previous
//
#include <hip/hip_runtime.h>

typedef unsigned short ushort_t;
typedef __attribute__((ext_vector_type(8))) short short8;
typedef __attribute__((ext_vector_type(4))) float floatx4;

#define DD 256
#define LL 3
#define GG 4
#define KK 128
#define UU 64
#define OUTN 10
#define HSTRIDE 264   // 256 + 8 bf16 pad; 528B row stride
#define MROWS 128     // rows per block
#define NT 2          // 16-col tiles per wave (8 waves x 32 cols = 256)

__device__ __forceinline__ ushort_t f2bf(float f) {
  unsigned u = __builtin_bit_cast(unsigned, f);
  u = (u + 0x7FFFu + ((u >> 16) & 1u)) >> 16;
  return (ushort_t)u;
}

// pack two f32 -> two bf16: 2 adds + 1 v_perm_b32
__device__ __forceinline__ unsigned pack_bf2(float lo, float hi) {
  unsigned a = __builtin_bit_cast(unsigned, hi) + 0x8000u;
  unsigned b = __builtin_bit_cast(unsigned, lo) + 0x8000u;
  return __builtin_amdgcn_perm(a, b, 0x07060302u);
}

// tanh(x) = 1 - 2/(e^{2x}+1); branch-free, exact at overflow
__device__ __forceinline__ float fast_tanh(float x) {
  float e = __builtin_amdgcn_exp2f(x * 2.885390081777927f);
  return __builtin_fmaf(-2.0f, __builtin_amdgcn_rcpf(e + 1.0f), 1.0f);
}

// FRAG-MAJOR operand layouts (the only change vs the 110us baseline):
// ATF[l][T][ks][lane][8] bf16, T = n>>4 (16 col-tiles), ks = k>>5,
// lane = quad*16 + l16, elem j -> (n = T*16 + l16, k = ks*32 + quad*8 + j).
// A-fragment load in fused = one contiguous 1KB global_load_dwordx4 per wave
// (was: 16 cache lines 512B apart per load -> ~4x-below-peak L2 stream).
// WF[ks][lane][8] likewise for W_out^T (o = l16 rows, o<10 else 0).
__global__ __launch_bounds__(256) void prep_kernel(
    const int* __restrict__ idx, const float* __restrict__ W,
    const float* __restrict__ Wout, ushort_t* __restrict__ ATF,
    ushort_t* __restrict__ WF) {
  int b = blockIdx.x;
  int t = threadIdx.x;
  if (b < LL * DD) {
    int l = b >> 8, n = b & 255, g = n >> 6, u = n & 63;
    __shared__ int sidx[KK];
    __shared__ float sw[KK];
    if (t < KK) {
      sidx[t] = idx[(l * GG + g) * KK + t];
      sw[t]   = W[((size_t)((l * GG + g) * KK + t)) * UU + u];
    }
    __syncthreads();
    float s = 0.f;
#pragma unroll 8
    for (int j = 0; j < KK; j++) s += (sidx[j] == t) ? sw[j] : 0.f;
    // scatter into frag-major position (k = t)
    int T = n >> 4, nl = n & 15;
    int ks = t >> 5, q = (t >> 3) & 3, j = t & 7;
    ATF[((((l * 16 + T) * 8 + ks) * 64) + q * 16 + nl) * 8 + j] = f2bf(s);
  } else {
    int e2 = (b - LL * DD) * 256 + t;
    int n = e2 >> 8, k = e2 & 255;   // n = output col (o), k = input dim
    int ks = k >> 5, q = (k >> 3) & 3, j = k & 7;
    WF[((ks * 64) + q * 16 + n) * 8 + j] =
        (n < OUTN) ? f2bf(Wout[k * OUTN + n]) : (ushort_t)0;
  }
}

// Identical structure to the 110us baseline (wave = 128 rows x 32 cols,
// MT=8 rolling-b, NT=2, depth-1 a-prefetch) -- only A addressing changed
// to the frag-major stream: wf[nt] = ATF[l][wave*2+nt][ks][lane].
__global__ __launch_bounds__(512, 4) void fused_kernel(
    const float* __restrict__ x, const float* __restrict__ bias,
    const float* __restrict__ bout, const ushort_t* __restrict__ ATF,
    const ushort_t* __restrict__ WF, float* __restrict__ out) {
  __shared__ ushort_t hbuf[MROWS * HSTRIDE];  // 67584 B -> 2 blocks/CU

  const int tid  = threadIdx.x;
  const int wave = tid >> 6;     // 0..7: N-cols [wave*32, wave*32+32)
  const int lane = tid & 63;
  const int quad = lane >> 4;
  const int l16  = lane & 15;
  const long row0 = (long)blockIdx.x * MROWS;

  // ---- stage x tile (128 x 256 fp32) -> bf16 LDS ----
  const float4* xv = (const float4*)(x + row0 * DD);
#pragma unroll
  for (int i = 0; i < 16; i++) {
    int f  = tid + i * 512;      // 0..8191 float4s, 64 per row
    int r  = f >> 6;
    int c4 = f & 63;
    float4 v = xv[r * 64 + c4];
    uint2 w;
    w.x = pack_bf2(v.x, v.y);
    w.y = pack_bf2(v.z, v.w);
    *(uint2*)&hbuf[r * HSTRIDE + c4 * 4] = w;
  }
  __syncthreads();

  // ---- 3 levels. Operand-swap: Aop = AT rows (u), Bop = h rows (m).
  // D: col=l16 -> m_local, row=quad*4+r -> u_local. Bias folded into acc init.
#pragma unroll 1
  for (int l = 0; l < 3; l++) {
    // frag-major A: contiguous 1KB per (nt,ks) frag, sequential in ks
    const ushort_t* Ab = ATF + l * 65536 + wave * 8192 + lane * 8;
    const ushort_t* hsrc = hbuf + l16 * HSTRIDE + quad * 8;

    floatx4 acc[8][NT];
#pragma unroll
    for (int nt = 0; nt < NT; nt++) {
      float4 bv = *(const float4*)&bias[l * DD + wave * 32 + nt * 16 + quad * 4];
      floatx4 ini = {bv.x, bv.y, bv.z, bv.w};
#pragma unroll
      for (int mt = 0; mt < 8; mt++) acc[mt][nt] = ini;
    }

    short8 wf[NT], wfn[NT];
#pragma unroll
    for (int nt = 0; nt < NT; nt++) wf[nt] = *(const short8*)&Ab[nt * 4096];

#pragma unroll
    for (int ks = 0; ks < 8; ks++) {
      if (ks < 7) {
#pragma unroll
        for (int nt = 0; nt < NT; nt++)
          wfn[nt] = *(const short8*)&Ab[nt * 4096 + (ks + 1) * 512];
      }
      // hand-staggered LDS reads: only 2 bf frags live at once
      short8 bfc = *(const short8*)&hsrc[0 * 16 * HSTRIDE + ks * 32];
#pragma unroll
      for (int mt = 0; mt < 8; mt++) {
        short8 bfn;
        if (mt < 7) bfn = *(const short8*)&hsrc[(mt + 1) * 16 * HSTRIDE + ks * 32];
        acc[mt][0] = __builtin_amdgcn_mfma_f32_16x16x32_bf16(wf[0], bfc, acc[mt][0], 0, 0, 0);
        acc[mt][1] = __builtin_amdgcn_mfma_f32_16x16x32_bf16(wf[1], bfc, acc[mt][1], 0, 0, 0);
        bfc = bfn;
      }
#pragma unroll
      for (int nt = 0; nt < NT; nt++) wf[nt] = wfn[nt];
    }
    __syncthreads();  // all hbuf reads done before overwrite

    // epilogue: lane holds 4 consecutive u for row m = mt*16+l16 -> 8B writes
#pragma unroll
    for (int nt = 0; nt < NT; nt++) {
#pragma unroll
      for (int mt = 0; mt < 8; mt++) {
        uint2 w;
        w.x = pack_bf2(fast_tanh(acc[mt][nt][0]), fast_tanh(acc[mt][nt][1]));
        w.y = pack_bf2(fast_tanh(acc[mt][nt][2]), fast_tanh(acc[mt][nt][3]));
        *(uint2*)&hbuf[(mt * 16 + l16) * HSTRIDE + wave * 32 + nt * 16 + quad * 4] = w;
      }
    }
    __syncthreads();
  }

  // ---- final: Aop = WF rows (o), frag-major; 16 rows per wave ----
  short8 wof[8];
#pragma unroll
  for (int ks = 0; ks < 8; ks++)
    wof[ks] = *(const short8*)&WF[ks * 512 + lane * 8];

  floatx4 accf = {0.f, 0.f, 0.f, 0.f};
#pragma unroll
  for (int ks = 0; ks < 8; ks++) {
    short8 bfr = *(const short8*)&hbuf[(wave * 16 + l16) * HSTRIDE + ks * 32 + quad * 8];
    accf = __builtin_amdgcn_mfma_f32_16x16x32_bf16(wof[ks], bfr, accf, 0, 0, 0);
  }
  const long obase = (row0 + wave * 16 + l16) * OUTN;
  if (quad < 2) {
    float4 p = {accf[0] + bout[quad * 4 + 0], accf[1] + bout[quad * 4 + 1],
                accf[2] + bout[quad * 4 + 2], accf[3] + bout[quad * 4 + 3]};
    *(float4*)&out[obase + quad * 4] = p;
  } else if (quad == 2) {
    float2 p = {accf[0] + bout[8], accf[1] + bout[9]};
    *(float2*)&out[obase + 8] = p;
  }
}

extern "C" void kernel_launch(void* const* d_in, const int* in_sizes, int n_in,
                              void* d_out, int out_size, void* d_ws, size_t ws_size,
                              hipStream_t stream) {
  const float* x    = (const float*)d_in[0];   // (131072, 256) fp32
  const int*   idx  = (const int*)d_in[1];     // (3, 4, 128) int32
  const float* W    = (const float*)d_in[2];   // (3, 4, 128, 64) fp32
  const float* b    = (const float*)d_in[3];   // (3, 4, 64) fp32
  const float* Wout = (const float*)d_in[4];   // (256, 10) fp32
  const float* bout = (const float*)d_in[5];   // (10,) fp32
  float* out = (float*)d_out;                  // (131072, 10) fp32

  ushort_t* ATF = (ushort_t*)d_ws;             // 3*16*8*64*8 bf16 = 384 KB
  ushort_t* WF  = ATF + LL * 16 * 8 * 64 * 8;  // 8*64*8 bf16 = 8 KB

  prep_kernel<<<LL * DD + 16, 256, 0, stream>>>(idx, W, Wout, ATF, WF);
  fused_kernel<<<131072 / MROWS, 512, 0, stream>>>(x, b, bout, ATF, WF, out);
}